// Round 2
// baseline (300.980 us; speedup 1.0000x reference)
//
#include <hip/hip_runtime.h>
#include <hip/hip_bf16.h>

// ---------------------------------------------------------------------------
// T5 MHA: B=2, S=2048, D_FF=1024, H=16, DK=64, INNER=1024
// Precision plan: QK^T path carried at ~fp24 effective via bf16 hi+lo splits
// (W-split proj GEMMs -> hi/lo qh,kh -> 3-chain QK MFMA). V path plain bf16.
// ---------------------------------------------------------------------------

typedef __attribute__((ext_vector_type(8))) short short8_t;   // 8 bf16 (4 VGPR)
typedef __attribute__((ext_vector_type(4))) short short4_t;
typedef __attribute__((ext_vector_type(4))) float f32x4_t;

#define SEQ 2048
#define HEADS 16
#define DK 64
#define DFF 1024

__device__ __forceinline__ unsigned short f32_to_bf16(float f) {
  unsigned int u = __float_as_uint(f);
  u += 0x7FFFu + ((u >> 16) & 1u);   // round-to-nearest-even
  return (unsigned short)(u >> 16);
}
__device__ __forceinline__ float bf16_to_f32(unsigned short h) {
  return __uint_as_float(((unsigned int)h) << 16);
}

__device__ __forceinline__ void gload_lds16(const void* g, void* l) {
  // async global->LDS, 16B per lane; LDS dest = wave-uniform base + lane*16
  __builtin_amdgcn_global_load_lds(
      (__attribute__((address_space(1))) void*)(g),
      (__attribute__((address_space(3))) void*)(l), 16, 0, 0);
}

// ---------------------------------------------------------------------------
// fp32 -> bf16 (plain) and fp32 -> bf16 hi+lo (split) converters
// ---------------------------------------------------------------------------
__global__ void cvt_f32_bf16_kernel(const float* __restrict__ in,
                                    short* __restrict__ out, int n) {
  int i = (blockIdx.x * 256 + threadIdx.x) * 4;
  if (i >= n) return;
  float4 f = *(const float4*)(in + i);
  short4_t s;
  s[0] = (short)f32_to_bf16(f.x);
  s[1] = (short)f32_to_bf16(f.y);
  s[2] = (short)f32_to_bf16(f.z);
  s[3] = (short)f32_to_bf16(f.w);
  *(short4_t*)(out + i) = s;
}

__global__ void cvt_split_kernel(const float* __restrict__ in,
                                 short* __restrict__ hi,
                                 short* __restrict__ lo, int n) {
  int i = (blockIdx.x * 256 + threadIdx.x) * 4;
  if (i >= n) return;
  float4 f = *(const float4*)(in + i);
  short4_t h, l;
  float ff[4] = {f.x, f.y, f.z, f.w};
#pragma unroll
  for (int j = 0; j < 4; ++j) {
    unsigned short hh = f32_to_bf16(ff[j]);
    h[j] = (short)hh;
    l[j] = (short)f32_to_bf16(ff[j] - bf16_to_f32(hh));
  }
  *(short4_t*)(hi + i) = h;
  *(short4_t*)(lo + i) = l;
}

// ---------------------------------------------------------------------------
// Plain GEMM C[M,N] = A[M,K] @ Bw[N,K]^T (bf16 in, fp32 accum)
// 128x128 tile, BK=32, 256 thr (4 waves, 64x64 each = 4x4 16x16 frags)
// EPI 0: bf16 head-split [B,H,S,64]; EPI 1: fp32 row-major
// ---------------------------------------------------------------------------
template <int EPI>
__global__ __launch_bounds__(256, 2) void gemm_bt(
    const short* __restrict__ A, const short* __restrict__ Bw,
    void* __restrict__ Cout, int M, int N, int K) {
  __shared__ short As[128 * 32];
  __shared__ short Bs[128 * 32];

  const int tid = threadIdx.x;
  const int w = tid >> 6, l = tid & 63, g = l >> 4, c = l & 15;
  const int wr = w >> 1, wc = w & 1;
  const int m0 = blockIdx.y * 128, n0 = blockIdx.x * 128;

  f32x4_t acc[4][4] = {};

  for (int k0 = 0; k0 < K; k0 += 32) {
#pragma unroll
    for (int j = 0; j < 2; ++j) {
      int e = (w * 2 + j) * 512 + l * 8;
      int r = e >> 5, cc = e & 31;
      gload_lds16(A + (size_t)(m0 + r) * K + k0 + cc, &As[(w * 2 + j) * 512]);
      gload_lds16(Bw + (size_t)(n0 + r) * K + k0 + cc, &Bs[(w * 2 + j) * 512]);
    }
    __syncthreads();

    short8_t a[4], b[4];
#pragma unroll
    for (int mi = 0; mi < 4; ++mi)
      a[mi] = *(const short8_t*)(&As[(wr * 64 + mi * 16 + c) * 32 + g * 8]);
#pragma unroll
    for (int ni = 0; ni < 4; ++ni)
      b[ni] = *(const short8_t*)(&Bs[(wc * 64 + ni * 16 + c) * 32 + g * 8]);
#pragma unroll
    for (int mi = 0; mi < 4; ++mi)
#pragma unroll
      for (int ni = 0; ni < 4; ++ni)
        acc[mi][ni] = __builtin_amdgcn_mfma_f32_16x16x32_bf16(
            a[mi], b[ni], acc[mi][ni], 0, 0, 0);
    __syncthreads();
  }

  // D layout: col = lane&15, row = (lane>>4)*4 + reg  (measured m89/m91)
  if (EPI == 0) {
    short* O = (short*)Cout;
#pragma unroll
    for (int mi = 0; mi < 4; ++mi) {
#pragma unroll
      for (int ni = 0; ni < 4; ++ni) {
        int col = n0 + wc * 64 + ni * 16 + c;
        int hh = col >> 6, dd = col & 63;
#pragma unroll
        for (int j = 0; j < 4; ++j) {
          int row = m0 + wr * 64 + mi * 16 + g * 4 + j;
          int bb = row >> 11, ss = row & 2047;
          O[(((size_t)bb * HEADS + hh) * SEQ + ss) * DK + dd] =
              (short)f32_to_bf16(acc[mi][ni][j]);
        }
      }
    }
  } else {
    float* O = (float*)Cout;
#pragma unroll
    for (int mi = 0; mi < 4; ++mi) {
#pragma unroll
      for (int ni = 0; ni < 4; ++ni) {
        int col = n0 + wc * 64 + ni * 16 + c;
#pragma unroll
        for (int j = 0; j < 4; ++j) {
          int row = m0 + wr * 64 + mi * 16 + g * 4 + j;
          O[(size_t)row * N + col] = acc[mi][ni][j];
        }
      }
    }
  }
}

// ---------------------------------------------------------------------------
// Split-B GEMM: C = A @ (Bh+Bl)^T, 2 MFMA chains; out = bf16 hi+lo head-split
// ---------------------------------------------------------------------------
__global__ __launch_bounds__(256, 2) void gemm_bt_split(
    const short* __restrict__ A, const short* __restrict__ Bh,
    const short* __restrict__ Bl, short* __restrict__ Ohi,
    short* __restrict__ Olo, int M, int N, int K) {
  __shared__ short As[128 * 32];
  __shared__ short Bsh[128 * 32];
  __shared__ short Bsl[128 * 32];

  const int tid = threadIdx.x;
  const int w = tid >> 6, l = tid & 63, g = l >> 4, c = l & 15;
  const int wr = w >> 1, wc = w & 1;
  const int m0 = blockIdx.y * 128, n0 = blockIdx.x * 128;

  f32x4_t acc[4][4] = {};

  for (int k0 = 0; k0 < K; k0 += 32) {
#pragma unroll
    for (int j = 0; j < 2; ++j) {
      int e = (w * 2 + j) * 512 + l * 8;
      int r = e >> 5, cc = e & 31;
      gload_lds16(A + (size_t)(m0 + r) * K + k0 + cc, &As[(w * 2 + j) * 512]);
      gload_lds16(Bh + (size_t)(n0 + r) * K + k0 + cc, &Bsh[(w * 2 + j) * 512]);
      gload_lds16(Bl + (size_t)(n0 + r) * K + k0 + cc, &Bsl[(w * 2 + j) * 512]);
    }
    __syncthreads();

    short8_t a[4], bh[4], bl[4];
#pragma unroll
    for (int mi = 0; mi < 4; ++mi)
      a[mi] = *(const short8_t*)(&As[(wr * 64 + mi * 16 + c) * 32 + g * 8]);
#pragma unroll
    for (int ni = 0; ni < 4; ++ni) {
      bh[ni] = *(const short8_t*)(&Bsh[(wc * 64 + ni * 16 + c) * 32 + g * 8]);
      bl[ni] = *(const short8_t*)(&Bsl[(wc * 64 + ni * 16 + c) * 32 + g * 8]);
    }
#pragma unroll
    for (int mi = 0; mi < 4; ++mi)
#pragma unroll
      for (int ni = 0; ni < 4; ++ni) {
        acc[mi][ni] = __builtin_amdgcn_mfma_f32_16x16x32_bf16(
            a[mi], bh[ni], acc[mi][ni], 0, 0, 0);
        acc[mi][ni] = __builtin_amdgcn_mfma_f32_16x16x32_bf16(
            a[mi], bl[ni], acc[mi][ni], 0, 0, 0);
      }
    __syncthreads();
  }

#pragma unroll
  for (int mi = 0; mi < 4; ++mi) {
#pragma unroll
    for (int ni = 0; ni < 4; ++ni) {
      int col = n0 + wc * 64 + ni * 16 + c;
      int hh = col >> 6, dd = col & 63;
#pragma unroll
      for (int j = 0; j < 4; ++j) {
        int row = m0 + wr * 64 + mi * 16 + g * 4 + j;
        int bb = row >> 11, ss = row & 2047;
        size_t idx = (((size_t)bb * HEADS + hh) * SEQ + ss) * DK + dd;
        float x = acc[mi][ni][j];
        unsigned short xh = f32_to_bf16(x);
        Ohi[idx] = (short)xh;
        Olo[idx] = (short)f32_to_bf16(x - bf16_to_f32(xh));
      }
    }
  }
}

// ---------------------------------------------------------------------------
// Flash attention, hi/lo Q,K (3-chain QK^T). Grid: (B*H, S/128). 256 thr.
// qh*/kh*: [B,H,S,64] bf16 hi+lo. vh: bf16. mask fp32. ctx out bf16 [B,S,1024].
// T5: NO 1/sqrt(d) scaling, additive mask.
// ---------------------------------------------------------------------------
__global__ __launch_bounds__(256, 2) void attn_kernel(
    const short* __restrict__ qhh, const short* __restrict__ qhl,
    const short* __restrict__ khh, const short* __restrict__ khl,
    const short* __restrict__ vh, const float* __restrict__ mask,
    short* __restrict__ ctx) {
  const int bh = blockIdx.x;
  const int b = bh >> 4;
  const int h = bh & 15;
  const int qt = blockIdx.y;
  const int tid = threadIdx.x;
  const int w = tid >> 6, l = tid & 63, g = l >> 4, c = l & 15;

  __shared__ short Ksh[64 * 72];      // K chunk hi, padded stride 72
  __shared__ short Ksl[64 * 72];      // K chunk lo
  __shared__ short Vt[64 * 72];       // V chunk transposed [d][kv]
  __shared__ short Ps[4][32 * 72];    // per-wave P tile [q][kv]

  const short* Kbh = khh + (size_t)bh * SEQ * DK;
  const short* Kbl = khl + (size_t)bh * SEQ * DK;
  const short* Vb = vh + (size_t)bh * SEQ * DK;
  const int qrow0 = qt * 128 + w * 32;
  const short* Qbh = qhh + ((size_t)bh * SEQ + qrow0) * DK;
  const short* Qbl = qhl + ((size_t)bh * SEQ + qrow0) * DK;
  const float* Mb = mask + (size_t)b * SEQ * SEQ + (size_t)qrow0 * SEQ;
  short* psw = &Ps[w][0];

  // Q fragments in registers (rows mi*16+c, k = ks*32 + g*8)
  short8_t qfh[2][2], qfl[2][2];
#pragma unroll
  for (int mi = 0; mi < 2; ++mi)
#pragma unroll
    for (int ks = 0; ks < 2; ++ks) {
      qfh[mi][ks] = *(const short8_t*)(Qbh + (size_t)(mi * 16 + c) * DK + ks * 32 + g * 8);
      qfl[mi][ks] = *(const short8_t*)(Qbl + (size_t)(mi * 16 + c) * DK + ks * 32 + g * 8);
    }

  f32x4_t o[2][4] = {};
  float mrun[2][4], lrun[2][4];
#pragma unroll
  for (int mi = 0; mi < 2; ++mi)
#pragma unroll
    for (int j = 0; j < 4; ++j) { mrun[mi][j] = -1e30f; lrun[mi][j] = 0.f; }

  for (int kv0 = 0; kv0 < SEQ; kv0 += 64) {
    __syncthreads();
#pragma unroll
    for (int it = 0; it < 2; ++it) {
      int e = (it * 256 + tid) * 8;
      int r = e >> 6, cc = e & 63;
      *(short8_t*)(&Ksh[r * 72 + cc]) =
          *(const short8_t*)(Kbh + (size_t)(kv0 + r) * DK + cc);
      *(short8_t*)(&Ksl[r * 72 + cc]) =
          *(const short8_t*)(Kbl + (size_t)(kv0 + r) * DK + cc);
      short8_t vvv = *(const short8_t*)(Vb + (size_t)(kv0 + r) * DK + cc);
#pragma unroll
      for (int i = 0; i < 8; ++i) Vt[(cc + i) * 72 + r] = vvv[i];
    }
    __syncthreads();

    // S = Q K^T : 3 chains (hi*hi + hi*lo + lo*hi)
    f32x4_t sa[2][4] = {};
#pragma unroll
    for (int ks = 0; ks < 2; ++ks) {
#pragma unroll
      for (int ni = 0; ni < 4; ++ni) {
        short8_t bh_ = *(const short8_t*)(&Ksh[(ni * 16 + c) * 72 + ks * 32 + g * 8]);
        short8_t bl_ = *(const short8_t*)(&Ksl[(ni * 16 + c) * 72 + ks * 32 + g * 8]);
#pragma unroll
        for (int mi = 0; mi < 2; ++mi) {
          sa[mi][ni] = __builtin_amdgcn_mfma_f32_16x16x32_bf16(
              qfh[mi][ks], bh_, sa[mi][ni], 0, 0, 0);
          sa[mi][ni] = __builtin_amdgcn_mfma_f32_16x16x32_bf16(
              qfh[mi][ks], bl_, sa[mi][ni], 0, 0, 0);
          sa[mi][ni] = __builtin_amdgcn_mfma_f32_16x16x32_bf16(
              qfl[mi][ks], bh_, sa[mi][ni], 0, 0, 0);
        }
      }
    }
    // + additive mask (fp32)
#pragma unroll
    for (int mi = 0; mi < 2; ++mi)
#pragma unroll
      for (int ni = 0; ni < 4; ++ni)
#pragma unroll
        for (int j = 0; j < 4; ++j)
          sa[mi][ni][j] += Mb[(size_t)(mi * 16 + g * 4 + j) * SEQ + kv0 + ni * 16 + c];

    // online softmax (row reduce across the 16-lane group)
#pragma unroll
    for (int mi = 0; mi < 2; ++mi) {
#pragma unroll
      for (int j = 0; j < 4; ++j) {
        float t = fmaxf(fmaxf(sa[mi][0][j], sa[mi][1][j]),
                        fmaxf(sa[mi][2][j], sa[mi][3][j]));
        t = fmaxf(t, __shfl_xor(t, 1));
        t = fmaxf(t, __shfl_xor(t, 2));
        t = fmaxf(t, __shfl_xor(t, 4));
        t = fmaxf(t, __shfl_xor(t, 8));
        float mold = mrun[mi][j];
        float mnew = fmaxf(mold, t);
        float scale = __expf(mold - mnew);
        mrun[mi][j] = mnew;
        lrun[mi][j] *= scale;
#pragma unroll
        for (int di = 0; di < 4; ++di) o[mi][di][j] *= scale;
#pragma unroll
        for (int ni = 0; ni < 4; ++ni) {
          float p = __expf(sa[mi][ni][j] - mnew);
          lrun[mi][j] += p;
          psw[(mi * 16 + g * 4 + j) * 72 + ni * 16 + c] = (short)f32_to_bf16(p);
        }
      }
    }

    // O += P V
#pragma unroll
    for (int ks = 0; ks < 2; ++ks) {
      short8_t pa[2];
#pragma unroll
      for (int mi = 0; mi < 2; ++mi)
        pa[mi] = *(const short8_t*)(&psw[(mi * 16 + c) * 72 + ks * 32 + g * 8]);
#pragma unroll
      for (int di = 0; di < 4; ++di) {
        short8_t bv = *(const short8_t*)(&Vt[(di * 16 + c) * 72 + ks * 32 + g * 8]);
#pragma unroll
        for (int mi = 0; mi < 2; ++mi)
          o[mi][di] = __builtin_amdgcn_mfma_f32_16x16x32_bf16(
              pa[mi], bv, o[mi][di], 0, 0, 0);
      }
    }
  }

  // finalize
#pragma unroll
  for (int mi = 0; mi < 2; ++mi)
#pragma unroll
    for (int j = 0; j < 4; ++j) {
      float s = lrun[mi][j];
      s += __shfl_xor(s, 1);
      s += __shfl_xor(s, 2);
      s += __shfl_xor(s, 4);
      s += __shfl_xor(s, 8);
      lrun[mi][j] = 1.f / s;
    }
  short* Cb = ctx + ((size_t)b * SEQ + qrow0) * DFF + h * DK;
#pragma unroll
  for (int mi = 0; mi < 2; ++mi)
#pragma unroll
    for (int di = 0; di < 4; ++di)
#pragma unroll
      for (int j = 0; j < 4; ++j) {
        float val = o[mi][di][j] * lrun[mi][j];
        Cb[(size_t)(mi * 16 + g * 4 + j) * DFF + di * 16 + c] =
            (short)f32_to_bf16(val);
      }
}

// ---------------------------------------------------------------------------
extern "C" void kernel_launch(void* const* d_in, const int* in_sizes, int n_in,
                              void* d_out, int out_size, void* d_ws, size_t ws_size,
                              hipStream_t stream) {
  const float* q    = (const float*)d_in[0];
  const float* k    = (const float*)d_in[1];
  const float* v    = (const float*)d_in[2];
  const float* mask = (const float*)d_in[3];
  const float* Wq   = (const float*)d_in[4];
  const float* Wk   = (const float*)d_in[5];
  const float* Wv   = (const float*)d_in[6];
  const float* Wo   = (const float*)d_in[7];
  float* out = (float*)d_out;

  const size_t NQ = 4194304;   // 4096*1024
  const size_t NW = 1048576;   // 1024*1024
  short* ws   = (short*)d_ws;
  short* qbf  = ws;            // A0; reused as kh_h after proj Q
  short* kbf  = ws + NQ;       // A1; reused as vh after proj K
  short* vbf  = ws + 2 * NQ;   // A2; reused as ctx after proj V
  short* qh_h = ws + 3 * NQ;
  short* qh_l = ws + 4 * NQ;
  short* kh_l = ws + 5 * NQ;
  short* wq_h = ws + 6 * NQ;
  short* wq_l = wq_h + NW;
  short* wk_h = wq_l + NW;
  short* wk_l = wk_h + NW;
  short* wvb  = wk_l + NW;
  short* wob  = wvb + NW;      // total 6*NQ + 6*NW shorts = 62.9 MB

  short* kh_h = qbf;   // aliases (stream-ordered, safe)
  short* vhp  = kbf;
  short* ctx  = vbf;

  cvt_f32_bf16_kernel<<<4096, 256, 0, stream>>>(q, qbf, (int)NQ);
  cvt_f32_bf16_kernel<<<4096, 256, 0, stream>>>(k, kbf, (int)NQ);
  cvt_f32_bf16_kernel<<<4096, 256, 0, stream>>>(v, vbf, (int)NQ);
  cvt_split_kernel<<<1024, 256, 0, stream>>>(Wq, wq_h, wq_l, (int)NW);
  cvt_split_kernel<<<1024, 256, 0, stream>>>(Wk, wk_h, wk_l, (int)NW);
  cvt_f32_bf16_kernel<<<1024, 256, 0, stream>>>(Wv, wvb, (int)NW);
  cvt_f32_bf16_kernel<<<1024, 256, 0, stream>>>(Wo, wob, (int)NW);

  dim3 gg(8, 32);   // N/128, M/128
  gemm_bt_split<<<gg, 256, 0, stream>>>(qbf, wq_h, wq_l, qh_h, qh_l, 4096, 1024, 1024);
  gemm_bt_split<<<gg, 256, 0, stream>>>(kbf, wk_h, wk_l, kh_h, kh_l, 4096, 1024, 1024);
  gemm_bt<0><<<gg, 256, 0, stream>>>(vbf, wvb, vhp, 4096, 1024, 1024);

  attn_kernel<<<dim3(32, 16), 256, 0, stream>>>(qh_h, qh_l, kh_h, kh_l, vhp, mask, ctx);

  gemm_bt<1><<<gg, 256, 0, stream>>>(ctx, wob, out, 4096, 1024, 1024);
}